// Round 7
// baseline (146.281 us; speedup 1.0000x reference)
//
#include <hip/hip_runtime.h>
#include <hip/hip_bf16.h>

// Joiner: out[b,t,u,v] = tanh(enc[b,t,:] + pred[b,u,:]) . W[v,:] + bias[v]
// B=8 T=512 U=128 D=256 V=128, fp32 in/out.
// Block = (b, 16-t chunk, u-half of 64), 512 thr = 8 waves (2u x 4v grid),
// wave = 32u x 32v via v_mfma_f32_32x32x16_bf16 with A=joint(u), B=W(v):
// D col = v = lane&31 -> every store instr writes 2 full 128B lines.
// pred(bf16) + W B-frags + bias persist in registers. tanh tile double-
// buffered in XOR-swizzled LDS; one s_barrier/iter, lgkmcnt-only wait
// (stores never drained in-loop).

constexpr int Bn = 8, Tn = 512, Un = 128, Dn = 256, Vn = 128;
constexpr int TCHUNK = 16;

typedef __attribute__((ext_vector_type(8))) short bf16x8;    // 8 bf16 = 4 VGPRs
typedef __attribute__((ext_vector_type(16))) float f32x16;   // 32x32 accum

static __device__ __forceinline__ unsigned short f2bf(float f) {
    unsigned int u = __float_as_uint(f);
    return (unsigned short)((u + 0x7fffu + ((u >> 16) & 1u)) >> 16);
}
static __device__ __forceinline__ float bf2f(unsigned short h) {
    return __uint_as_float(((unsigned int)h) << 16);
}
// tanh(x) = 1 - 2/(exp(2x)+1); med3 clamp; (R5-proven form)
static __device__ __forceinline__ float fast_tanh(float x) {
    float t = __builtin_amdgcn_fmed3f(x, -8.f, 8.f);
    float e = __expf(2.f * t);
    float r = __builtin_amdgcn_rcpf(e + 1.f);
    return __builtin_fmaf(-2.f, r, 1.f);
}

__global__ __launch_bounds__(256) void cvtW_kernel(const float* __restrict__ W,
                                                   unsigned short* __restrict__ Wb) {
    int i = blockIdx.x * 256 + threadIdx.x;          // 32 blocks * 256 * 4 elems = 32768
    float4 v = ((const float4*)W)[i];
    unsigned short r0 = f2bf(v.x), r1 = f2bf(v.y), r2 = f2bf(v.z), r3 = f2bf(v.w);
    unsigned long long packed = (unsigned long long)r0 | ((unsigned long long)r1 << 16) |
                                ((unsigned long long)r2 << 32) | ((unsigned long long)r3 << 48);
    ((unsigned long long*)Wb)[i] = packed;
}

__global__ __launch_bounds__(512, 4) void joiner_kernel(
    const float* __restrict__ enc,         // [B,T,D]
    const float* __restrict__ pred,        // [B,U,D]
    const unsigned short* __restrict__ Wb, // [V,D] bf16 bits
    const float* __restrict__ bias,        // [V]
    float* __restrict__ out)               // [B,T,U,V]
{
    // joint tile: 64 u-rows x 256 d (bf16) as 16B granules, granule ^= (row&7)
    // swizzle (0 conflicts measured on the write pattern in R2/R4).
    __shared__ unsigned short jointS[2][64 * 256];   // 2 x 32 KB

    const int bid = blockIdx.x;            // (b*32 + tc)*2 + uh
    const int uh  = bid & 1;
    const int tc  = (bid >> 1) & 31;
    const int b   = bid >> 6;
    const int tid = threadIdx.x;
    const int w   = tid >> 6;              // 8 waves: wv = w&3 (32 v), wu = w>>2 (32 u)
    const int wv  = w & 3;
    const int wu  = w >> 2;
    const int l   = tid & 63;
    const int l32 = l & 31;
    const int lk  = l >> 5;                // k-group (0..1) for 32x32x16 frags

    // phase-1 static mapping: thread owns rows {ub, ub+32} x 16 d at d0=db*16
    const int db = tid & 15;
    const int ub = tid >> 4;               // 0..31

    // ---- persistent state (loaded once per block) ----
    bf16x8 predR[2][2];                    // 2 rows x 16 d, bf16 (16 VGPR)
#pragma unroll
    for (int j = 0; j < 2; ++j) {
        const float* pr = pred + ((size_t)(b * Un + uh * 64 + ub + 32 * j)) * Dn + db * 16;
        float4 a0 = *(const float4*)(pr + 0);
        float4 a1 = *(const float4*)(pr + 4);
        float4 a2 = *(const float4*)(pr + 8);
        float4 a3 = *(const float4*)(pr + 12);
        bf16x8 q0, q1;
        q0[0] = (short)f2bf(a0.x); q0[1] = (short)f2bf(a0.y);
        q0[2] = (short)f2bf(a0.z); q0[3] = (short)f2bf(a0.w);
        q0[4] = (short)f2bf(a1.x); q0[5] = (short)f2bf(a1.y);
        q0[6] = (short)f2bf(a1.z); q0[7] = (short)f2bf(a1.w);
        q1[0] = (short)f2bf(a2.x); q1[1] = (short)f2bf(a2.y);
        q1[2] = (short)f2bf(a2.z); q1[3] = (short)f2bf(a2.w);
        q1[4] = (short)f2bf(a3.x); q1[5] = (short)f2bf(a3.y);
        q1[6] = (short)f2bf(a3.z); q1[7] = (short)f2bf(a3.w);
        predR[j][0] = q0; predR[j][1] = q1;
    }

    // W B-frags for this wave's 32 v cols: 16 k-frags x 4 VGPR = 64 VGPR.
    // B[k][n]: n = l32 (v), k = kf*16 + lk*8 + e (8 contiguous d).
    bf16x8 wfr[16];
#pragma unroll
    for (int kf = 0; kf < 16; ++kf)
        wfr[kf] = *(const bf16x8*)(Wb + (size_t)(wv * 32 + l32) * Dn + kf * 16 + lk * 8);

    const float bvs = bias[wv * 32 + l32];

    const size_t encBase = (size_t)(b * Tn + tc * TCHUNK) * Dn;

    // tanh(enc + pred) -> swizzled LDS tile (each value computed exactly once)
    auto write_tile = [&](unsigned short* buf, const float ev[16]) {
#pragma unroll
        for (int j = 0; j < 2; ++j) {
            const int r  = ub + 32 * j;
            const int sw = r & 7;
            bf16x8 o0, o1;
#pragma unroll
            for (int i = 0; i < 8; ++i)
                o0[i] = (short)f2bf(fast_tanh(ev[i] + bf2f((unsigned short)predR[j][0][i])));
#pragma unroll
            for (int i = 0; i < 8; ++i)
                o1[i] = (short)f2bf(fast_tanh(ev[8 + i] + bf2f((unsigned short)predR[j][1][i])));
            *(bf16x8*)&buf[((r * 32) + ((db * 2) ^ sw)) * 8]     = o0;
            *(bf16x8*)&buf[((r * 32) + ((db * 2 + 1) ^ sw)) * 8] = o1;
        }
    };
    auto load_enc = [&](int t_idx, float ev[16]) {
        const float* er = enc + encBase + (size_t)t_idx * Dn + db * 16;
        float4 a0 = *(const float4*)(er + 0);
        float4 a1 = *(const float4*)(er + 4);
        float4 a2 = *(const float4*)(er + 8);
        float4 a3 = *(const float4*)(er + 12);
        ev[0] = a0.x;  ev[1] = a0.y;  ev[2]  = a0.z;  ev[3]  = a0.w;
        ev[4] = a1.x;  ev[5] = a1.y;  ev[6]  = a1.z;  ev[7]  = a1.w;
        ev[8] = a2.x;  ev[9] = a2.y;  ev[10] = a2.z;  ev[11] = a2.w;
        ev[12] = a3.x; ev[13] = a3.y; ev[14] = a3.z;  ev[15] = a3.w;
    };

    // ---- prologue: tile 0 into buf 0 ----
    {
        float ev[16];
        load_enc(0, ev);
        write_tile(jointS[0], ev);
    }
    asm volatile("s_waitcnt lgkmcnt(0)" ::: "memory");
    __builtin_amdgcn_s_barrier();
    __builtin_amdgcn_sched_barrier(0);

    for (int ti = 0; ti < TCHUNK; ++ti) {
        const unsigned short* cur = jointS[ti & 1];

        // ---------- MFMA: A = joint (32 u rows) from LDS, B = W regs ----------
        // A[m][k]: m = wu*32 + l32 (u), k = kf*16 + lk*8 + e.
        f32x16 acc;
#pragma unroll
        for (int i = 0; i < 16; ++i) acc[i] = 0.f;

        const int arow = wu * 32 + l32;
        const int asw  = arow & 7;
#pragma unroll
        for (int kf = 0; kf < 16; ++kf) {
            bf16x8 afr = *(const bf16x8*)&cur[((arow * 32) + ((kf * 2 + lk) ^ asw)) * 8];
            acc = __builtin_amdgcn_mfma_f32_32x32x16_bf16(afr, wfr[kf], acc, 0, 0, 0);
        }

        // ---------- epilogue: bias + dword stores (2 full 128B lines/instr) ----------
        // D: row(u) = (i&3) + 8*(i>>2) + 4*lk, col(v) = l32.
        const size_t rowBase = (size_t)((b * Tn + tc * TCHUNK + ti) * Un + uh * 64);
        float* ob = out + (rowBase + wu * 32 + 4 * lk) * Vn + wv * 32 + l32;
#pragma unroll
        for (int i = 0; i < 16; ++i) {
            const int udelta = (i & 3) + 8 * (i >> 2);
            ob[(size_t)udelta * Vn] = acc[i] + bvs;
        }

        // ---------- next tanh tile into the other buffer ----------
        if (ti + 1 < TCHUNK) {
            float ev[16];
            load_enc(ti + 1, ev);          // L1-broadcast (all waves same row)
            write_tile(jointS[(ti + 1) & 1], ev);
            // barrier protects LDS only: wait ds ops, NOT the global stores
            asm volatile("s_waitcnt lgkmcnt(0)" ::: "memory");
            __builtin_amdgcn_s_barrier();
            __builtin_amdgcn_sched_barrier(0);
        }
    }
}

extern "C" void kernel_launch(void* const* d_in, const int* in_sizes, int n_in,
                              void* d_out, int out_size, void* d_ws, size_t ws_size,
                              hipStream_t stream) {
    const float* enc  = (const float*)d_in[0];
    const float* pred = (const float*)d_in[1];
    const float* W    = (const float*)d_in[2];
    const float* bias = (const float*)d_in[3];
    float* out = (float*)d_out;
    unsigned short* Wb = (unsigned short*)d_ws;   // 32768 bf16 = 64 KB

    cvtW_kernel<<<32, 256, 0, stream>>>(W, Wb);
    // grid = B * (T/TCHUNK) * 2 u-halves = 8 * 32 * 2 = 512 blocks
    joiner_kernel<<<512, 512, 0, stream>>>(enc, pred, Wb, bias, out);
}